// Round 5
// baseline (568.207 us; speedup 1.0000x reference)
//
#include <hip/hip_runtime.h>
#include <hip/hip_bf16.h>
#include <cstdint>

#define L_SEQ 2048
#define HID   4096
#define NH    32
#define NKV   8
#define HD    128
#define MAXP  4096
#define QKVD  6144          // fused Q|K|V projection width
#define K_OFF 4096
#define V_OFF 5120

using bf16_t = __hip_bfloat16;
typedef __bf16 bf16x8 __attribute__((ext_vector_type(8)));
typedef float  f32x4  __attribute__((ext_vector_type(4)));
typedef short  short4v __attribute__((ext_vector_type(4)));
typedef short  short8v __attribute__((ext_vector_type(8)));

__device__ __forceinline__ void async_copy16(void* lds, const void* g) {
  __builtin_amdgcn_global_load_lds(
      (__attribute__((address_space(1))) void*)g,
      (__attribute__((address_space(3))) void*)lds, 16, 0, 0);
}

__device__ __forceinline__ f32x4 MFMA16(bf16x8 a, bf16x8 b, f32x4 c) {
  return __builtin_amdgcn_mfma_f32_16x16x32_bf16(a, b, c, 0, 0, 0);
}

// ---------------- RMSNorm: x (L,HID) f32 -> h (L,HID) bf16 ----------------
__global__ __launch_bounds__(256) void rmsnorm_kernel(
    const float* __restrict__ x, const float* __restrict__ w,
    bf16_t* __restrict__ h) {
  int row = blockIdx.x, t = threadIdx.x;
  const float4* xv = (const float4*)(x + (size_t)row * HID);
  float4 v[4];
  float ss = 0.f;
#pragma unroll
  for (int i = 0; i < 4; i++) {
    v[i] = xv[i * 256 + t];
    ss += v[i].x * v[i].x + v[i].y * v[i].y + v[i].z * v[i].z + v[i].w * v[i].w;
  }
#pragma unroll
  for (int off = 32; off >= 1; off >>= 1) ss += __shfl_xor(ss, off, 64);
  __shared__ float red[4];
  if ((t & 63) == 0) red[t >> 6] = ss;
  __syncthreads();
  float rr = rsqrtf((red[0] + red[1] + red[2] + red[3]) * (1.0f / HID) + 1e-5f);
  const float4* wv = (const float4*)w;
  bf16_t* hr = h + (size_t)row * HID;
#pragma unroll
  for (int i = 0; i < 4; i++) {
    float4 wl = wv[i * 256 + t];
    bf16_t tmp[4];
    tmp[0] = __float2bfloat16(v[i].x * rr * wl.x);
    tmp[1] = __float2bfloat16(v[i].y * rr * wl.y);
    tmp[2] = __float2bfloat16(v[i].z * rr * wl.z);
    tmp[3] = __float2bfloat16(v[i].w * rr * wl.w);
    *(short4v*)(hr + (size_t)(i * 256 + t) * 4) = *(short4v*)tmp;
  }
}

// ---------------- f32 -> bf16 convert (single source) ----------------
__global__ __launch_bounds__(256) void cvt_bf16_kernel(
    const float* __restrict__ src, bf16_t* __restrict__ dst) {
  size_t i = ((size_t)blockIdx.x * 256 + threadIdx.x) * 8;
  float4 a = *(const float4*)(src + i);
  float4 b = *(const float4*)(src + i + 4);
  bf16_t tmp[8] = {__float2bfloat16(a.x), __float2bfloat16(a.y),
                   __float2bfloat16(a.z), __float2bfloat16(a.w),
                   __float2bfloat16(b.x), __float2bfloat16(b.y),
                   __float2bfloat16(b.z), __float2bfloat16(b.w)};
  *(short8v*)(dst + i) = *(short8v*)tmp;
}

// ---------------- fused Wq|Wk|Wv f32 -> bf16 (one launch) -----------------
// dst rows: [0,4096) <- Wq, [4096,5120) <- Wk, [5120,6144) <- Wv.
// Each block covers 2048 consecutive elements = half a 4096-row; never
// straddles a source boundary.
__global__ __launch_bounds__(256) void cvtqkv_kernel(
    const float* __restrict__ Wq, const float* __restrict__ Wk,
    const float* __restrict__ Wv, bf16_t* __restrict__ dst) {
  size_t i = ((size_t)blockIdx.x * 256 + threadIdx.x) * 8;
  size_t row = i >> 12;  // / HID
  const float* src;
  size_t off;
  if (row < 4096)      { src = Wq; off = i; }
  else if (row < 5120) { src = Wk; off = i - ((size_t)4096 << 12); }
  else                 { src = Wv; off = i - ((size_t)5120 << 12); }
  float4 a = *(const float4*)(src + off);
  float4 b = *(const float4*)(src + off + 4);
  bf16_t tmp[8] = {__float2bfloat16(a.x), __float2bfloat16(a.y),
                   __float2bfloat16(a.z), __float2bfloat16(a.w),
                   __float2bfloat16(b.x), __float2bfloat16(b.y),
                   __float2bfloat16(b.z), __float2bfloat16(b.w)};
  *(short8v*)(dst + i) = *(short8v*)tmp;
}

// ---------------- split-K partial reduce: out += P ------------------------
__global__ __launch_bounds__(256) void addp_kernel(
    float* __restrict__ out, const float* __restrict__ P) {
  size_t i = ((size_t)blockIdx.x * 256 + threadIdx.x) * 4;
  float4 o = *(float4*)(out + i);
  float4 p = *(const float4*)(P + i);
  o.x += p.x; o.y += p.y; o.z += p.z; o.w += p.w;
  *(float4*)(out + i) = o;
}

// ---- GEMM 256x256 tile, BK=64, 8-phase schedule with PIPELINED ds_reads --
// OUT_MODE 0: C bf16.  OUT_MODE 3: split-K over blockIdx.z (z=0 writes
// Cf = acc + resid, z=1 writes Pout = acc; addp_kernel sums after).
// K = per-block extent, LDA = row stride of A/B (full K dim).
#define STR2_(x) #x
#define STR_(x) STR2_(x)

template <int OUT_MODE>
__global__ __launch_bounds__(512, 2) void gemm256_kernel(
    const bf16_t* __restrict__ A, const bf16_t* __restrict__ B,
    bf16_t* __restrict__ Cb, float* __restrict__ Cf,
    const float* __restrict__ resid, float* __restrict__ Pout,
    int N, int K, int LDA) {
  __shared__ alignas(16) bf16_t As[2 * 2 * 8192];   // 64 KiB
  __shared__ alignas(16) bf16_t Bs[2 * 2 * 8192];   // 64 KiB

  const int t = threadIdx.x;
  const int l = t & 63;
  const int w = t >> 6;        // wave 0..7
  const int wm = w >> 2;       // 0..1  (A half / 128-row block)
  const int wn = w & 3;        // 0..3  (64-col block)
  const int wh = wn >> 1;      // B half
  const int wn1 = wn & 1;      // 64-row sub-block within B half
  const int lane15 = l & 15, quad = l >> 4;
  const int l7 = l & 7;

  const size_t koff = (size_t)blockIdx.z * K;
  const bf16_t* Ag = A + (size_t)blockIdx.y * 256 * LDA + koff;
  const bf16_t* Bg = B + (size_t)blockIdx.x * 256 * LDA + koff;

  const int srow = t >> 3;                 // staging row 0..63
  const int sgran = (t & 7) ^ (srow & 7);  // inverse-swizzled src granule
  const int wbase = w << 9;                // per-wave linear LDS dest (elems)

  const bf16_t* pAg = Ag + (size_t)srow * LDA + sgran * 8;
  const bf16_t* pBg = Bg + (size_t)srow * LDA + sgran * 8;
  const size_t row64 = (size_t)64 * LDA;

#define STAGE(PL, UOFF, ldsh) do {                                            \
    const bf16_t* _g = (PL) + (UOFF);                                         \
    async_copy16((ldsh) + wbase, _g);                                         \
    async_copy16((ldsh) + wbase + 4096, _g + row64);                          \
  } while (0)

#define ASD(sl, h) (&As[(sl) * 16384 + (h) * 8192])
#define BSD(sl, h) (&Bs[(sl) * 16384 + (h) * 8192])

  typedef __attribute__((address_space(3))) char* lds_b;
  lds_b asb = (lds_b)As;
  lds_b bsb = (lds_b)Bs;
  const unsigned aoff0 = (unsigned)(wm * 16384 + lane15 * 128 + ((quad ^ l7) << 4));
  const unsigned boff0 = (unsigned)(wh * 16384 + (wn1 * 64 + lane15) * 128 + ((quad ^ l7) << 4));
  lds_b pa0s0 = asb + aoff0;
  lds_b pa1s0 = asb + (aoff0 ^ 64u);
  lds_b pa0s1 = pa0s0 + 32768;
  lds_b pa1s1 = pa1s0 + 32768;
  lds_b pb0s0 = bsb + boff0;
  lds_b pb1s0 = bsb + (boff0 ^ 64u);
  lds_b pb0s1 = pb0s0 + 32768;
  lds_b pb1s1 = pb1s0 + 32768;

#define DSR(dst, p, IMM) \
  asm volatile("ds_read_b128 %0, %1 offset:" STR_(IMM) : "=v"(dst) : "v"(p))

#define RA(dst, P0, P1, I0, I1, I2, I3) do {                                  \
    DSR(dst[0][0], P0, I0); DSR(dst[0][1], P1, I0);                           \
    DSR(dst[1][0], P0, I1); DSR(dst[1][1], P1, I1);                           \
    DSR(dst[2][0], P0, I2); DSR(dst[2][1], P1, I2);                           \
    DSR(dst[3][0], P0, I3); DSR(dst[3][1], P1, I3); } while (0)
#define RB(dst, P0, P1, I0, I1) do {                                          \
    DSR(dst[0][0], P0, I0); DSR(dst[0][1], P1, I0);                           \
    DSR(dst[1][0], P0, I1); DSR(dst[1][1], P1, I1); } while (0)

#define BAR() do { asm volatile("s_barrier");                                 \
    __builtin_amdgcn_sched_barrier(0); } while (0)
#define LGKM(NW) do { asm volatile("s_waitcnt lgkmcnt(" STR_(NW) ")");        \
    __builtin_amdgcn_sched_barrier(0); } while (0)
#define VMW(NW) asm volatile("s_waitcnt vmcnt(" STR_(NW) ")")

#define MMQ(IB, JB, AF, BF) do {                                              \
    __builtin_amdgcn_s_setprio(1);                                            \
    _Pragma("unroll") for (int i = 0; i < 4; i++)                             \
    _Pragma("unroll") for (int j = 0; j < 2; j++) {                           \
      acc[(IB)+i][(JB)+j] = MFMA16(AF[i][0], BF[j][0], acc[(IB)+i][(JB)+j]);  \
      acc[(IB)+i][(JB)+j] = MFMA16(AF[i][1], BF[j][1], acc[(IB)+i][(JB)+j]);  \
    }                                                                         \
    __builtin_amdgcn_s_setprio(0);                                            \
    __builtin_amdgcn_sched_barrier(0);                                        \
  } while (0)

  const size_t u128 = (size_t)128 * LDA;
  const int NTT = K >> 6;       // K-tiles of 64
  const int niter = NTT >> 1;

  f32x4 acc[8][4] = {};
  bf16x8 a[4][2], a2[4][2], blo[2][2], bhi[2][2];

  STAGE(pBg, 0,          BSD(0, 0));
  STAGE(pAg, 0,          ASD(0, 0));
  STAGE(pBg, u128,       BSD(0, 1));
  STAGE(pAg, u128,       ASD(0, 1));
  STAGE(pBg, 64,         BSD(1, 0));
  STAGE(pAg, 64,         ASD(1, 0));
  VMW(4);
  BAR();
  RA(a, pa0s0, pa1s0, 0, 2048, 4096, 6144);
  RB(blo, pb0s0, pb1s0, 0, 2048);

  for (int it = 0; it < niter; ++it) {
    const int tb = it * 2;
    const size_t kc1 = (size_t)((tb + 1) << 6);
    const size_t kc2 = (size_t)(((tb + 2 < NTT) ? tb + 2 : NTT - 1) << 6);
    const size_t kc3 = (size_t)(((tb + 3 < NTT) ? tb + 3 : NTT - 1) << 6);
    // ph1
    STAGE(pBg, u128 + kc1, BSD(1, 1));
    BAR();
    RB(bhi, pb0s0, pb1s0, 4096, 6144);
    LGKM(4);
    MMQ(0, 0, a, blo);
    BAR();
    // ph2
    STAGE(pAg, u128 + kc1, ASD(1, 1));
    BAR();
    RA(a2, pa0s0, pa1s0, 8192, 10240, 12288, 14336);
    LGKM(8);
    MMQ(0, 2, a, bhi);
    BAR();
    // ph3
    STAGE(pBg, kc2, BSD(0, 0));
    BAR();
    LGKM(0);
    MMQ(4, 0, a2, blo);
    BAR();
    // ph4
    STAGE(pAg, kc2, ASD(0, 0));
    VMW(4);
    BAR();
    RA(a, pa0s1, pa1s1, 0, 2048, 4096, 6144);
    RB(blo, pb0s1, pb1s1, 0, 2048);
    LGKM(12);
    MMQ(4, 2, a2, bhi);
    BAR();
    // ph5
    STAGE(pBg, u128 + kc2, BSD(0, 1));
    BAR();
    RB(bhi, pb0s1, pb1s1, 4096, 6144);
    LGKM(4);
    MMQ(0, 0, a, blo);
    BAR();
    // ph6
    STAGE(pAg, u128 + kc2, ASD(0, 1));
    BAR();
    RA(a2, pa0s1, pa1s1, 8192, 10240, 12288, 14336);
    LGKM(8);
    MMQ(0, 2, a, bhi);
    BAR();
    // ph7
    STAGE(pBg, kc3, BSD(1, 0));
    BAR();
    LGKM(0);
    MMQ(4, 0, a2, blo);
    BAR();
    // ph8
    STAGE(pAg, kc3, ASD(1, 0));
    VMW(4);
    BAR();
    if (it + 1 < niter) {
      RA(a, pa0s0, pa1s0, 0, 2048, 4096, 6144);
      RB(blo, pb0s0, pb1s0, 0, 2048);
    }
    LGKM(12);
    MMQ(4, 2, a2, bhi);
    BAR();
  }
  VMW(0);  // drain tail-clamped junk DMAs before workgroup retires

  const int row0 = blockIdx.y * 256 + wm * 128 + quad * 4;
  const int col0 = blockIdx.x * 256 + wn * 64 + lane15;
#pragma unroll
  for (int i = 0; i < 8; i++)
#pragma unroll
    for (int j = 0; j < 4; j++)
#pragma unroll
      for (int r = 0; r < 4; r++) {
        size_t idx = (size_t)(row0 + i * 16 + r) * N + col0 + j * 16;
        if (OUT_MODE == 0) {
          Cb[idx] = __float2bfloat16(acc[i][j][r]);
        } else {  // OUT_MODE == 3: split-K
          if (blockIdx.z == 0)
            Cf[idx] = acc[i][j][r] + resid[idx];
          else
            Pout[idx] = acc[i][j][r];
        }
      }
#undef STAGE
#undef ASD
#undef BSD
#undef DSR
#undef RA
#undef RB
#undef BAR
#undef LGKM
#undef VMW
#undef MMQ
}

// ---------------- RoPE in-place on fused qkv (L, QKVD) --------------------
__global__ __launch_bounds__(256) void rope_kernel(
    bf16_t* __restrict__ qkv,
    const float* __restrict__ cosT, const float* __restrict__ sinT,
    float* __restrict__ kc_out) {
  int idx = blockIdx.x * 256 + threadIdx.x;  // L*(NH+NKV)*64
  int d = idx & 63;
  int rest = idx >> 6;
  int hh = rest % (NH + NKV);
  int pos = rest / (NH + NKV);
  float c = cosT[pos * HD + d];
  float s = sinT[pos * HD + d];
  bf16_t* b = (hh < NH)
      ? qkv + (size_t)pos * QKVD + hh * HD
      : qkv + (size_t)pos * QKVD + K_OFF + (hh - NH) * HD;
  float x1 = __bfloat162float(b[d]);
  float x2 = __bfloat162float(b[d + 64]);
  float o1 = x1 * c - x2 * s;
  float o2 = x2 * c + x1 * s;
  b[d] = __float2bfloat16(o1);
  b[d + 64] = __float2bfloat16(o2);
  if (hh >= NH) {
    float* kc = kc_out + (size_t)pos * (NKV * HD) + (hh - NH) * HD;
    kc[d] = o1;
    kc[d + 64] = o2;
  }
}

// ---------------- V transpose via LDS + v_cache fp32 write ----------------
__global__ __launch_bounds__(256) void vtrans_kernel(
    const bf16_t* __restrict__ qkv, float* __restrict__ vc_out,
    bf16_t* __restrict__ vT) {
  __shared__ alignas(16) short Ts[64 * 64];
  int kvh = blockIdx.x, pb = blockIdx.y, db = blockIdx.z;
  int t = threadIdx.x;
  int r = t & 63;
  int c4 = t >> 6;
  const short* src = (const short*)(qkv + (size_t)(pb * 64 + r) * QKVD +
                                    V_OFF + kvh * HD + db * 64 + c4 * 16);
  short8v v0 = *(const short8v*)src;
  short8v v1 = *(const short8v*)(src + 8);
  float* vo = vc_out + (size_t)(pb * 64 + r) * (NKV * HD) + kvh * HD + db * 64 + c4 * 16;
  float tmpf[16];
#pragma unroll
  for (int j = 0; j < 8; j++) {
    tmpf[j]     = __uint_as_float(((unsigned)(unsigned short)v0[j]) << 16);
    tmpf[j + 8] = __uint_as_float(((unsigned)(unsigned short)v1[j]) << 16);
  }
#pragma unroll
  for (int j = 0; j < 4; j++)
    ((float4*)vo)[j] = make_float4(tmpf[j * 4], tmpf[j * 4 + 1],
                                   tmpf[j * 4 + 2], tmpf[j * 4 + 3]);
  int cs = c4 ^ (r & 3);
  *(short8v*)&Ts[r * 64 + cs * 16] = v0;
  *(short8v*)&Ts[r * 64 + cs * 16 + 8] = v1;
  __syncthreads();
  int dr = t & 63;
  int pc = t >> 6;
  short vals[16];
#pragma unroll
  for (int j = 0; j < 16; j++) {
    int pos = pc * 16 + j;
    int cc = (dr >> 4) ^ (pos & 3);
    vals[j] = Ts[pos * 64 + cc * 16 + (dr & 15)];
  }
  short* dst = (short*)(vT + ((size_t)kvh * HD + db * 64 + dr) * L_SEQ + pb * 64 + pc * 16);
  *(short8v*)dst = *(short8v*)&vals[0];
  *(short8v*)(dst + 8) = *(short8v*)&vals[8];
}

// ---------------- cache tail copy (pos >= L) ------------------------------
__global__ __launch_bounds__(256) void cache_tail_kernel(
    const float* __restrict__ kc_in, const float* __restrict__ vc_in,
    float* __restrict__ kc_out, float* __restrict__ vc_out) {
  size_t base = (size_t)L_SEQ * NKV * HD;
  size_t i = base + ((size_t)blockIdx.x * 256 + threadIdx.x) * 4;
  *(float4*)(kc_out + i) = *(const float4*)(kc_in + i);
  *(float4*)(vc_out + i) = *(const float4*)(vc_in + i);
}

// ---------------- Flash attention: 64-row Q tiles, 2 blocks/CU ------------
// (unchanged from round 4 -- verified working)
__global__ __launch_bounds__(256, 2) void attn_kernel(
    const bf16_t* __restrict__ qkv, const bf16_t* __restrict__ vT,
    bf16_t* __restrict__ attn) {
  int h = blockIdx.x;
  int pb = blockIdx.y;           // 0..15
  int kvh = h >> 2;
  int t = threadIdx.x, w = t >> 6, l = t & 63;
  int lane15 = l & 15, quad = l >> 4;

  __shared__ alignas(16) bf16_t Ks[2][16 * 512];
  __shared__ alignas(16) bf16_t Vs[2][16 * 512];
  __shared__ alignas(16) bf16_t Ps[4][16 * 68];

  const float scale = 0.08838834764831845f;

#define STAGEATTN(KB, BUF) do {                                               \
    _Pragma("unroll") for (int kk_ = 0; kk_ < 4; kk_++)                       \
      async_copy16(&Ks[BUF][(w * 4 + kk_) * 512],                             \
                   qkv + (size_t)((KB) * 64 + w * 16 + lane15) * QKVD +       \
                       K_OFF + kvh * HD + kk_ * 32 + quad * 8);               \
    _Pragma("unroll") for (int j_ = 0; j_ < 4; j_++) {                        \
      int tt_ = w * 2 + (j_ >> 1), kt_ = j_ & 1;                              \
      async_copy16(&Vs[BUF][(tt_ * 2 + kt_) * 512],                           \
                   vT + ((size_t)kvh * HD + tt_ * 16 + lane15) * L_SEQ +      \
                       (KB) * 64 + kt_ * 32 + quad * 8);                      \
    }                                                                         \
  } while (0)

  for (int sel = 0; sel < 2; ++sel) {
    const int qb = sel ? 31 - pb : pb;   // 64-row Q tile index

    bf16x8 aq[4];
#pragma unroll
    for (int kk = 0; kk < 4; kk++)
      aq[kk] = *(const bf16x8*)(qkv +
          (size_t)(qb * 64 + w * 16 + lane15) * QKVD +
          h * HD + kk * 32 + quad * 8);

    f32x4 o[8] = {};
    float lsum[4] = {};
    const int nk = qb + 1;

    STAGEATTN(0, 0);
    for (int kblk = 0; kblk < nk; kblk++) {
      const int cur = kblk & 1;
      if (kblk + 1 < nk) {
        STAGEATTN(kblk + 1, cur ^ 1);
        asm volatile("s_waitcnt vmcnt(8)");
      } else {
        asm volatile("s_waitcnt vmcnt(0)");
      }
      __builtin_amdgcn_s_barrier();
      __builtin_amdgcn_sched_barrier(0);

      f32x4 sacc[4] = {};
      __builtin_amdgcn_s_setprio(1);
#pragma unroll
      for (int n = 0; n < 4; n++)
#pragma unroll
        for (int kk = 0; kk < 4; kk++) {
          bf16x8 b = *(const bf16x8*)&Ks[cur][(n * 4 + kk) * 512 + l * 8];
          sacc[n] = MFMA16(aq[kk], b, sacc[n]);
        }
      __builtin_amdgcn_s_setprio(0);

      bool maskblk = (kblk == qb);
#pragma unroll
      for (int n = 0; n < 4; n++) {
        int col = kblk * 64 + n * 16 + lane15;
#pragma unroll
        for (int r = 0; r < 4; r++) {
          float p = __expf(sacc[n][r] * scale);
          if (maskblk && col > (qb * 64 + w * 16 + quad * 4 + r)) p = 0.f;
          lsum[r] += p;
          Ps[w][(quad * 4 + r) * 68 + n * 16 + lane15] = __float2bfloat16(p);
        }
      }

      __builtin_amdgcn_s_setprio(1);
#pragma unroll
      for (int kt2 = 0; kt2 < 2; kt2++) {
        bf16x8 ap = *(const bf16x8*)&Ps[w][lane15 * 68 + kt2 * 32 + quad * 8];
#pragma unroll
        for (int tt = 0; tt < 8; tt++) {
          bf16x8 b = *(const bf16x8*)&Vs[cur][(tt * 2 + kt2) * 512 + l * 8];
          o[tt] = MFMA16(ap, b, o[tt]);
        }
      }
      __builtin_amdgcn_s_setprio(0);
      __builtin_amdgcn_s_barrier();
    }

    float inv[4];
#pragma unroll
    for (int r = 0; r < 4; r++) {
      float s = lsum[r];
#pragma unroll
      for (int off = 1; off < 16; off <<= 1) s += __shfl_xor(s, off, 64);
      inv[r] = 1.f / s;
    }
    int qrow0 = qb * 64 + w * 16;
#pragma unroll
    for (int tt = 0; tt < 8; tt++) {
      int col = h * HD + tt * 16 + lane15;
#pragma unroll
      for (int r = 0; r < 4; r++)
        attn[(size_t)(qrow0 + quad * 4 + r) * HID + col] =
            __float2bfloat16(o[tt][r] * inv[r]);
    }
  }
#undef STAGEATTN
}

// ---------------- Launch --------------------------------------------------
extern "C" void kernel_launch(void* const* d_in, const int* in_sizes, int n_in,
                              void* d_out, int out_size, void* d_ws, size_t ws_size,
                              hipStream_t stream) {
  const float* x    = (const float*)d_in[0];
  const float* cosT = (const float*)d_in[1];
  const float* sinT = (const float*)d_in[2];
  const float* kc_in = (const float*)d_in[5];
  const float* vc_in = (const float*)d_in[6];
  const float* ln_w  = (const float*)d_in[7];
  const float* Wq = (const float*)d_in[8];
  const float* Wk = (const float*)d_in[9];
  const float* Wv = (const float*)d_in[10];
  const float* Wo = (const float*)d_in[11];

  float* out    = (float*)d_out;
  float* kc_out = out + (size_t)L_SEQ * HID;
  float* vc_out = kc_out + (size_t)MAXP * NKV * HD;

  // Workspace map (peak 92 MiB):
  //  [0,16M):   h_bf, later attn_bf (h dead after QKV GEMM)
  //  [16M,64M): Wqkv_bf (48 MB); after QKV GEMM: Wo_bf [16M,48M)
  //  [48M,80M): Psplit (f32 32 MiB, split-K partial; region dead at Wo-GEMM
  //             time: Wqkv tail dead, qkv_bf [64M,88M) dead after attn)
  //  [64M,88M): qkv_bf (L x 6144 bf16, 24 MB) -- live QKV GEMM .. attn
  //  [88M,92M): vT_bf (NKV,HD,L bf16, 4 MB)   -- live vtrans .. attn
  char* ws = (char*)d_ws;
  bf16_t* h_bf    = (bf16_t*)(ws + 0);
  bf16_t* attn_bf = (bf16_t*)(ws + 0);
  bf16_t* Wqkv_bf = (bf16_t*)(ws + 16777216);
  bf16_t* Wo_bf   = (bf16_t*)(ws + 16777216);
  float*  Psplit  = (float*)(ws + 50331648);
  bf16_t* qkv_bf  = (bf16_t*)(ws + 67108864);
  bf16_t* vT_bf   = (bf16_t*)(ws + 92274688);

  rmsnorm_kernel<<<L_SEQ, 256, 0, stream>>>(x, ln_w, h_bf);
  // fused Wq|Wk|Wv convert: 6144*4096 elems, one launch
  cvtqkv_kernel<<<(QKVD * HID) / (8 * 256), 256, 0, stream>>>(
      Wq, Wk, Wv, Wqkv_bf);

  // Fused QKV = h @ Wqkv^T -> qkv_bf (L, 6144); 24x8 = 192 blocks, 1/CU
  gemm256_kernel<0><<<dim3(QKVD / 256, L_SEQ / 256, 1), 512, 0, stream>>>(
      h_bf, Wqkv_bf, qkv_bf, nullptr, nullptr, nullptr, QKVD, HID, HID);

  rope_kernel<<<(L_SEQ * (NH + NKV) * 64) / 256, 256, 0, stream>>>(
      qkv_bf, cosT, sinT, kc_out);
  vtrans_kernel<<<dim3(NKV, L_SEQ / 64, HD / 64), 256, 0, stream>>>(
      qkv_bf, vc_out, vT_bf);
  cache_tail_kernel<<<((MAXP - L_SEQ) * NKV * HD) / (4 * 256), 256, 0, stream>>>(
      kc_in, vc_in, kc_out, vc_out);

  cvt_bf16_kernel<<<(HID * HID) / (8 * 256), 256, 0, stream>>>(Wo, Wo_bf);

  // balanced 64-row-pair attention: 32 heads x 16 = 512 blocks, 2/CU
  attn_kernel<<<dim3(NH, 16), 256, 0, stream>>>(qkv_bf, vT_bf, attn_bf);

  // out = attn @ Wo^T + x, split-K x2: 16x8x2 = 256 blocks = 1/CU exactly.
  // z=0: out = acc(K first half) + x ; z=1: Psplit = acc(K second half)
  gemm256_kernel<3><<<dim3(HID / 256, L_SEQ / 256, 2), 512, 0, stream>>>(
      attn_bf, Wo_bf, nullptr, out, x, Psplit, HID, HID / 2, HID);
  // out += Psplit
  addp_kernel<<<(L_SEQ * HID) / (4 * 256), 256, 0, stream>>>(out, Psplit);
}

// Round 6
// 537.841 us; speedup vs baseline: 1.0565x; 1.0565x over previous
//
#include <hip/hip_runtime.h>
#include <hip/hip_bf16.h>
#include <cstdint>

#define L_SEQ 2048
#define HID   4096
#define NH    32
#define NKV   8
#define HD    128
#define MAXP  4096
#define QKVD  6144          // fused Q|K|V projection width
#define K_OFF 4096
#define V_OFF 5120

using bf16_t = __hip_bfloat16;
typedef __bf16 bf16x8 __attribute__((ext_vector_type(8)));
typedef float  f32x4  __attribute__((ext_vector_type(4)));
typedef short  short4v __attribute__((ext_vector_type(4)));
typedef short  short8v __attribute__((ext_vector_type(8)));

__device__ __forceinline__ void async_copy16(void* lds, const void* g) {
  __builtin_amdgcn_global_load_lds(
      (__attribute__((address_space(1))) void*)g,
      (__attribute__((address_space(3))) void*)lds, 16, 0, 0);
}

__device__ __forceinline__ f32x4 MFMA16(bf16x8 a, bf16x8 b, f32x4 c) {
  return __builtin_amdgcn_mfma_f32_16x16x32_bf16(a, b, c, 0, 0, 0);
}

// ---------------- RMSNorm: x (L,HID) f32 -> h (L,HID) bf16 ----------------
__global__ __launch_bounds__(256) void rmsnorm_kernel(
    const float* __restrict__ x, const float* __restrict__ w,
    bf16_t* __restrict__ h) {
  int row = blockIdx.x, t = threadIdx.x;
  const float4* xv = (const float4*)(x + (size_t)row * HID);
  float4 v[4];
  float ss = 0.f;
#pragma unroll
  for (int i = 0; i < 4; i++) {
    v[i] = xv[i * 256 + t];
    ss += v[i].x * v[i].x + v[i].y * v[i].y + v[i].z * v[i].z + v[i].w * v[i].w;
  }
#pragma unroll
  for (int off = 32; off >= 1; off >>= 1) ss += __shfl_xor(ss, off, 64);
  __shared__ float red[4];
  if ((t & 63) == 0) red[t >> 6] = ss;
  __syncthreads();
  float rr = rsqrtf((red[0] + red[1] + red[2] + red[3]) * (1.0f / HID) + 1e-5f);
  const float4* wv = (const float4*)w;
  bf16_t* hr = h + (size_t)row * HID;
#pragma unroll
  for (int i = 0; i < 4; i++) {
    float4 wl = wv[i * 256 + t];
    bf16_t tmp[4];
    tmp[0] = __float2bfloat16(v[i].x * rr * wl.x);
    tmp[1] = __float2bfloat16(v[i].y * rr * wl.y);
    tmp[2] = __float2bfloat16(v[i].z * rr * wl.z);
    tmp[3] = __float2bfloat16(v[i].w * rr * wl.w);
    *(short4v*)(hr + (size_t)(i * 256 + t) * 4) = *(short4v*)tmp;
  }
}

// ---------------- f32 -> bf16 convert (single source) ----------------
__global__ __launch_bounds__(256) void cvt_bf16_kernel(
    const float* __restrict__ src, bf16_t* __restrict__ dst) {
  size_t i = ((size_t)blockIdx.x * 256 + threadIdx.x) * 8;
  float4 a = *(const float4*)(src + i);
  float4 b = *(const float4*)(src + i + 4);
  bf16_t tmp[8] = {__float2bfloat16(a.x), __float2bfloat16(a.y),
                   __float2bfloat16(a.z), __float2bfloat16(a.w),
                   __float2bfloat16(b.x), __float2bfloat16(b.y),
                   __float2bfloat16(b.z), __float2bfloat16(b.w)};
  *(short8v*)(dst + i) = *(short8v*)tmp;
}

// ---------------- fused Wq|Wk|Wv f32 -> bf16 (one launch) -----------------
__global__ __launch_bounds__(256) void cvtqkv_kernel(
    const float* __restrict__ Wq, const float* __restrict__ Wk,
    const float* __restrict__ Wv, bf16_t* __restrict__ dst) {
  size_t i = ((size_t)blockIdx.x * 256 + threadIdx.x) * 8;
  size_t row = i >> 12;  // / HID
  const float* src;
  size_t off;
  if (row < 4096)      { src = Wq; off = i; }
  else if (row < 5120) { src = Wk; off = i - ((size_t)4096 << 12); }
  else                 { src = Wv; off = i - ((size_t)5120 << 12); }
  float4 a = *(const float4*)(src + off);
  float4 b = *(const float4*)(src + off + 4);
  bf16_t tmp[8] = {__float2bfloat16(a.x), __float2bfloat16(a.y),
                   __float2bfloat16(a.z), __float2bfloat16(a.w),
                   __float2bfloat16(b.x), __float2bfloat16(b.y),
                   __float2bfloat16(b.z), __float2bfloat16(b.w)};
  *(short8v*)(dst + i) = *(short8v*)tmp;
}

// ---- GEMM 256x256 tile, BK=64, 8-phase schedule with PIPELINED ds_reads --
// (round-4 verified structure: OUT_MODE 0 -> C bf16; 1 -> Cf = acc + resid)
#define STR2_(x) #x
#define STR_(x) STR2_(x)

template <int OUT_MODE>
__global__ __launch_bounds__(512, 2) void gemm256_kernel(
    const bf16_t* __restrict__ A, const bf16_t* __restrict__ B,
    bf16_t* __restrict__ Cb, float* __restrict__ Cf,
    const float* __restrict__ resid, int N, int K) {
  __shared__ alignas(16) bf16_t As[2 * 2 * 8192];   // 64 KiB
  __shared__ alignas(16) bf16_t Bs[2 * 2 * 8192];   // 64 KiB

  const int t = threadIdx.x;
  const int l = t & 63;
  const int w = t >> 6;        // wave 0..7
  const int wm = w >> 2;       // 0..1  (A half / 128-row block)
  const int wn = w & 3;        // 0..3  (64-col block)
  const int wh = wn >> 1;      // B half
  const int wn1 = wn & 1;      // 64-row sub-block within B half
  const int lane15 = l & 15, quad = l >> 4;
  const int l7 = l & 7;

  const bf16_t* Ag = A + (size_t)blockIdx.y * 256 * K;
  const bf16_t* Bg = B + (size_t)blockIdx.x * 256 * K;

  const int srow = t >> 3;                 // staging row 0..63
  const int sgran = (t & 7) ^ (srow & 7);  // inverse-swizzled src granule
  const int wbase = w << 9;                // per-wave linear LDS dest (elems)

  const bf16_t* pAg = Ag + (size_t)srow * K + sgran * 8;
  const bf16_t* pBg = Bg + (size_t)srow * K + sgran * 8;
  const size_t row64 = (size_t)64 * K;

#define STAGE(PL, UOFF, ldsh) do {                                            \
    const bf16_t* _g = (PL) + (UOFF);                                         \
    async_copy16((ldsh) + wbase, _g);                                         \
    async_copy16((ldsh) + wbase + 4096, _g + row64);                          \
  } while (0)

#define ASD(sl, h) (&As[(sl) * 16384 + (h) * 8192])
#define BSD(sl, h) (&Bs[(sl) * 16384 + (h) * 8192])

  typedef __attribute__((address_space(3))) char* lds_b;
  lds_b asb = (lds_b)As;
  lds_b bsb = (lds_b)Bs;
  const unsigned aoff0 = (unsigned)(wm * 16384 + lane15 * 128 + ((quad ^ l7) << 4));
  const unsigned boff0 = (unsigned)(wh * 16384 + (wn1 * 64 + lane15) * 128 + ((quad ^ l7) << 4));
  lds_b pa0s0 = asb + aoff0;
  lds_b pa1s0 = asb + (aoff0 ^ 64u);
  lds_b pa0s1 = pa0s0 + 32768;
  lds_b pa1s1 = pa1s0 + 32768;
  lds_b pb0s0 = bsb + boff0;
  lds_b pb1s0 = bsb + (boff0 ^ 64u);
  lds_b pb0s1 = pb0s0 + 32768;
  lds_b pb1s1 = pb1s0 + 32768;

#define DSR(dst, p, IMM) \
  asm volatile("ds_read_b128 %0, %1 offset:" STR_(IMM) : "=v"(dst) : "v"(p))

#define RA(dst, P0, P1, I0, I1, I2, I3) do {                                  \
    DSR(dst[0][0], P0, I0); DSR(dst[0][1], P1, I0);                           \
    DSR(dst[1][0], P0, I1); DSR(dst[1][1], P1, I1);                           \
    DSR(dst[2][0], P0, I2); DSR(dst[2][1], P1, I2);                           \
    DSR(dst[3][0], P0, I3); DSR(dst[3][1], P1, I3); } while (0)
#define RB(dst, P0, P1, I0, I1) do {                                          \
    DSR(dst[0][0], P0, I0); DSR(dst[0][1], P1, I0);                           \
    DSR(dst[1][0], P0, I1); DSR(dst[1][1], P1, I1); } while (0)

#define BAR() do { asm volatile("s_barrier");                                 \
    __builtin_amdgcn_sched_barrier(0); } while (0)
#define LGKM(NW) do { asm volatile("s_waitcnt lgkmcnt(" STR_(NW) ")");        \
    __builtin_amdgcn_sched_barrier(0); } while (0)
#define VMW(NW) asm volatile("s_waitcnt vmcnt(" STR_(NW) ")")

#define MMQ(IB, JB, AF, BF) do {                                              \
    __builtin_amdgcn_s_setprio(1);                                            \
    _Pragma("unroll") for (int i = 0; i < 4; i++)                             \
    _Pragma("unroll") for (int j = 0; j < 2; j++) {                           \
      acc[(IB)+i][(JB)+j] = MFMA16(AF[i][0], BF[j][0], acc[(IB)+i][(JB)+j]);  \
      acc[(IB)+i][(JB)+j] = MFMA16(AF[i][1], BF[j][1], acc[(IB)+i][(JB)+j]);  \
    }                                                                         \
    __builtin_amdgcn_s_setprio(0);                                            \
    __builtin_amdgcn_sched_barrier(0);                                        \
  } while (0)

  const size_t u128 = (size_t)128 * K;
  const int NTT = K >> 6;       // K-tiles of 64
  const int niter = NTT >> 1;

  f32x4 acc[8][4] = {};
  bf16x8 a[4][2], a2[4][2], blo[2][2], bhi[2][2];

  STAGE(pBg, 0,          BSD(0, 0));
  STAGE(pAg, 0,          ASD(0, 0));
  STAGE(pBg, u128,       BSD(0, 1));
  STAGE(pAg, u128,       ASD(0, 1));
  STAGE(pBg, 64,         BSD(1, 0));
  STAGE(pAg, 64,         ASD(1, 0));
  VMW(4);
  BAR();
  RA(a, pa0s0, pa1s0, 0, 2048, 4096, 6144);
  RB(blo, pb0s0, pb1s0, 0, 2048);

  for (int it = 0; it < niter; ++it) {
    const int tb = it * 2;
    const size_t kc1 = (size_t)((tb + 1) << 6);
    const size_t kc2 = (size_t)(((tb + 2 < NTT) ? tb + 2 : NTT - 1) << 6);
    const size_t kc3 = (size_t)(((tb + 3 < NTT) ? tb + 3 : NTT - 1) << 6);
    // ph1
    STAGE(pBg, u128 + kc1, BSD(1, 1));
    BAR();
    RB(bhi, pb0s0, pb1s0, 4096, 6144);
    LGKM(4);
    MMQ(0, 0, a, blo);
    BAR();
    // ph2
    STAGE(pAg, u128 + kc1, ASD(1, 1));
    BAR();
    RA(a2, pa0s0, pa1s0, 8192, 10240, 12288, 14336);
    LGKM(8);
    MMQ(0, 2, a, bhi);
    BAR();
    // ph3
    STAGE(pBg, kc2, BSD(0, 0));
    BAR();
    LGKM(0);
    MMQ(4, 0, a2, blo);
    BAR();
    // ph4
    STAGE(pAg, kc2, ASD(0, 0));
    VMW(4);
    BAR();
    RA(a, pa0s1, pa1s1, 0, 2048, 4096, 6144);
    RB(blo, pb0s1, pb1s1, 0, 2048);
    LGKM(12);
    MMQ(4, 2, a2, bhi);
    BAR();
    // ph5
    STAGE(pBg, u128 + kc2, BSD(0, 1));
    BAR();
    RB(bhi, pb0s1, pb1s1, 4096, 6144);
    LGKM(4);
    MMQ(0, 0, a, blo);
    BAR();
    // ph6
    STAGE(pAg, u128 + kc2, ASD(0, 1));
    BAR();
    RA(a2, pa0s1, pa1s1, 8192, 10240, 12288, 14336);
    LGKM(8);
    MMQ(0, 2, a, bhi);
    BAR();
    // ph7
    STAGE(pBg, kc3, BSD(1, 0));
    BAR();
    LGKM(0);
    MMQ(4, 0, a2, blo);
    BAR();
    // ph8
    STAGE(pAg, kc3, ASD(1, 0));
    VMW(4);
    BAR();
    if (it + 1 < niter) {
      RA(a, pa0s0, pa1s0, 0, 2048, 4096, 6144);
      RB(blo, pb0s0, pb1s0, 0, 2048);
    }
    LGKM(12);
    MMQ(4, 2, a2, bhi);
    BAR();
  }
  VMW(0);  // drain tail-clamped junk DMAs before workgroup retires

  const int row0 = blockIdx.y * 256 + wm * 128 + quad * 4;
  const int col0 = blockIdx.x * 256 + wn * 64 + lane15;
#pragma unroll
  for (int i = 0; i < 8; i++)
#pragma unroll
    for (int j = 0; j < 4; j++)
#pragma unroll
      for (int r = 0; r < 4; r++) {
        size_t idx = (size_t)(row0 + i * 16 + r) * N + col0 + j * 16;
        if (OUT_MODE == 0)
          Cb[idx] = __float2bfloat16(acc[i][j][r]);
        else
          Cf[idx] = acc[i][j][r] + resid[idx];
      }
#undef STAGE
#undef ASD
#undef BSD
#undef DSR
#undef RA
#undef RB
#undef BAR
#undef LGKM
#undef VMW
#undef MMQ
}

// ---- fused post-QKV processing: rope | vtrans | cache_tail in one launch -
// The three parts touch disjoint data: rope modifies Q|K columns of qkv and
// writes kc_out rows < L; vtrans reads V columns of qkv, writes vc_out rows
// < L and vT; cache_tail touches rows >= L.  Block ranges:
//   [0, 20480):        rope   (L*(NH+NKV)*64 / 256 elements-pairs)
//   [20480, 20992):    vtrans (NKV x L/64 x HD/64 = 512 tiles)
//   [20992, 23040):    cache_tail (2048 blocks)
#define ROPE_NBLK 20480
#define VT_NBLK   512
#define TAIL_NBLK 2048

__global__ __launch_bounds__(256) void postproc_kernel(
    bf16_t* __restrict__ qkv,
    const float* __restrict__ cosT, const float* __restrict__ sinT,
    float* __restrict__ kc_out, float* __restrict__ vc_out,
    bf16_t* __restrict__ vT,
    const float* __restrict__ kc_in, const float* __restrict__ vc_in) {
  __shared__ alignas(16) short Ts[64 * 64];
  int blk = blockIdx.x;
  int t = threadIdx.x;

  if (blk < ROPE_NBLK) {
    // ---------------- RoPE ----------------
    int idx = blk * 256 + t;
    int d = idx & 63;
    int rest = idx >> 6;
    int hh = rest % (NH + NKV);
    int pos = rest / (NH + NKV);
    float c = cosT[pos * HD + d];
    float s = sinT[pos * HD + d];
    bf16_t* b = (hh < NH)
        ? qkv + (size_t)pos * QKVD + hh * HD
        : qkv + (size_t)pos * QKVD + K_OFF + (hh - NH) * HD;
    float x1 = __bfloat162float(b[d]);
    float x2 = __bfloat162float(b[d + 64]);
    float o1 = x1 * c - x2 * s;
    float o2 = x2 * c + x1 * s;
    b[d] = __float2bfloat16(o1);
    b[d + 64] = __float2bfloat16(o2);
    if (hh >= NH) {
      float* kc = kc_out + (size_t)pos * (NKV * HD) + (hh - NH) * HD;
      kc[d] = o1;
      kc[d + 64] = o2;
    }
  } else if (blk < ROPE_NBLK + VT_NBLK) {
    // ---------------- V transpose + v_cache write ----------------
    int vb = blk - ROPE_NBLK;
    int kvh = vb & 7;
    int pb = (vb >> 3) & 31;
    int db = vb >> 8;
    int r = t & 63;
    int c4 = t >> 6;
    const short* src = (const short*)(qkv + (size_t)(pb * 64 + r) * QKVD +
                                      V_OFF + kvh * HD + db * 64 + c4 * 16);
    short8v v0 = *(const short8v*)src;
    short8v v1 = *(const short8v*)(src + 8);
    float* vo = vc_out + (size_t)(pb * 64 + r) * (NKV * HD) + kvh * HD + db * 64 + c4 * 16;
    float tmpf[16];
#pragma unroll
    for (int j = 0; j < 8; j++) {
      tmpf[j]     = __uint_as_float(((unsigned)(unsigned short)v0[j]) << 16);
      tmpf[j + 8] = __uint_as_float(((unsigned)(unsigned short)v1[j]) << 16);
    }
#pragma unroll
    for (int j = 0; j < 4; j++)
      ((float4*)vo)[j] = make_float4(tmpf[j * 4], tmpf[j * 4 + 1],
                                     tmpf[j * 4 + 2], tmpf[j * 4 + 3]);
    int cs = c4 ^ (r & 3);
    *(short8v*)&Ts[r * 64 + cs * 16] = v0;
    *(short8v*)&Ts[r * 64 + cs * 16 + 8] = v1;
    __syncthreads();
    int dr = t & 63;
    int pc = t >> 6;
    short vals[16];
#pragma unroll
    for (int j = 0; j < 16; j++) {
      int pos = pc * 16 + j;
      int cc = (dr >> 4) ^ (pos & 3);
      vals[j] = Ts[pos * 64 + cc * 16 + (dr & 15)];
    }
    short* dst = (short*)(vT + ((size_t)kvh * HD + db * 64 + dr) * L_SEQ + pb * 64 + pc * 16);
    *(short8v*)dst = *(short8v*)&vals[0];
    *(short8v*)(dst + 8) = *(short8v*)&vals[8];
  } else {
    // ---------------- cache tail copy (pos >= L) ----------------
    int cb = blk - (ROPE_NBLK + VT_NBLK);
    size_t base = (size_t)L_SEQ * NKV * HD;
    size_t i = base + ((size_t)cb * 256 + t) * 4;
    *(float4*)(kc_out + i) = *(const float4*)(kc_in + i);
    *(float4*)(vc_out + i) = *(const float4*)(vc_in + i);
  }
}

// ---------------- Flash attention: 64-row Q tiles, 2 blocks/CU ------------
// (unchanged from round 4 -- verified working)
__global__ __launch_bounds__(256, 2) void attn_kernel(
    const bf16_t* __restrict__ qkv, const bf16_t* __restrict__ vT,
    bf16_t* __restrict__ attn) {
  int h = blockIdx.x;
  int pb = blockIdx.y;           // 0..15
  int kvh = h >> 2;
  int t = threadIdx.x, w = t >> 6, l = t & 63;
  int lane15 = l & 15, quad = l >> 4;

  __shared__ alignas(16) bf16_t Ks[2][16 * 512];
  __shared__ alignas(16) bf16_t Vs[2][16 * 512];
  __shared__ alignas(16) bf16_t Ps[4][16 * 68];

  const float scale = 0.08838834764831845f;

#define STAGEATTN(KB, BUF) do {                                               \
    _Pragma("unroll") for (int kk_ = 0; kk_ < 4; kk_++)                       \
      async_copy16(&Ks[BUF][(w * 4 + kk_) * 512],                             \
                   qkv + (size_t)((KB) * 64 + w * 16 + lane15) * QKVD +       \
                       K_OFF + kvh * HD + kk_ * 32 + quad * 8);               \
    _Pragma("unroll") for (int j_ = 0; j_ < 4; j_++) {                        \
      int tt_ = w * 2 + (j_ >> 1), kt_ = j_ & 1;                              \
      async_copy16(&Vs[BUF][(tt_ * 2 + kt_) * 512],                           \
                   vT + ((size_t)kvh * HD + tt_ * 16 + lane15) * L_SEQ +      \
                       (KB) * 64 + kt_ * 32 + quad * 8);                      \
    }                                                                         \
  } while (0)

  for (int sel = 0; sel < 2; ++sel) {
    const int qb = sel ? 31 - pb : pb;   // 64-row Q tile index

    bf16x8 aq[4];
#pragma unroll
    for (int kk = 0; kk < 4; kk++)
      aq[kk] = *(const bf16x8*)(qkv +
          (size_t)(qb * 64 + w * 16 + lane15) * QKVD +
          h * HD + kk * 32 + quad * 8);

    f32x4 o[8] = {};
    float lsum[4] = {};
    const int nk = qb + 1;

    STAGEATTN(0, 0);
    for (int kblk = 0; kblk < nk; kblk++) {
      const int cur = kblk & 1;
      if (kblk + 1 < nk) {
        STAGEATTN(kblk + 1, cur ^ 1);
        asm volatile("s_waitcnt vmcnt(8)");
      } else {
        asm volatile("s_waitcnt vmcnt(0)");
      }
      __builtin_amdgcn_s_barrier();
      __builtin_amdgcn_sched_barrier(0);

      f32x4 sacc[4] = {};
      __builtin_amdgcn_s_setprio(1);
#pragma unroll
      for (int n = 0; n < 4; n++)
#pragma unroll
        for (int kk = 0; kk < 4; kk++) {
          bf16x8 b = *(const bf16x8*)&Ks[cur][(n * 4 + kk) * 512 + l * 8];
          sacc[n] = MFMA16(aq[kk], b, sacc[n]);
        }
      __builtin_amdgcn_s_setprio(0);

      bool maskblk = (kblk == qb);
#pragma unroll
      for (int n = 0; n < 4; n++) {
        int col = kblk * 64 + n * 16 + lane15;
#pragma unroll
        for (int r = 0; r < 4; r++) {
          float p = __expf(sacc[n][r] * scale);
          if (maskblk && col > (qb * 64 + w * 16 + quad * 4 + r)) p = 0.f;
          lsum[r] += p;
          Ps[w][(quad * 4 + r) * 68 + n * 16 + lane15] = __float2bfloat16(p);
        }
      }

      __builtin_amdgcn_s_setprio(1);
#pragma unroll
      for (int kt2 = 0; kt2 < 2; kt2++) {
        bf16x8 ap = *(const bf16x8*)&Ps[w][lane15 * 68 + kt2 * 32 + quad * 8];
#pragma unroll
        for (int tt = 0; tt < 8; tt++) {
          bf16x8 b = *(const bf16x8*)&Vs[cur][(tt * 2 + kt2) * 512 + l * 8];
          o[tt] = MFMA16(ap, b, o[tt]);
        }
      }
      __builtin_amdgcn_s_setprio(0);
      __builtin_amdgcn_s_barrier();
    }

    float inv[4];
#pragma unroll
    for (int r = 0; r < 4; r++) {
      float s = lsum[r];
#pragma unroll
      for (int off = 1; off < 16; off <<= 1) s += __shfl_xor(s, off, 64);
      inv[r] = 1.f / s;
    }
    int qrow0 = qb * 64 + w * 16;
#pragma unroll
    for (int tt = 0; tt < 8; tt++) {
      int col = h * HD + tt * 16 + lane15;
#pragma unroll
      for (int r = 0; r < 4; r++)
        attn[(size_t)(qrow0 + quad * 4 + r) * HID + col] =
            __float2bfloat16(o[tt][r] * inv[r]);
    }
  }
#undef STAGEATTN
}

// ---------------- Launch --------------------------------------------------
extern "C" void kernel_launch(void* const* d_in, const int* in_sizes, int n_in,
                              void* d_out, int out_size, void* d_ws, size_t ws_size,
                              hipStream_t stream) {
  const float* x    = (const float*)d_in[0];
  const float* cosT = (const float*)d_in[1];
  const float* sinT = (const float*)d_in[2];
  const float* kc_in = (const float*)d_in[5];
  const float* vc_in = (const float*)d_in[6];
  const float* ln_w  = (const float*)d_in[7];
  const float* Wq = (const float*)d_in[8];
  const float* Wk = (const float*)d_in[9];
  const float* Wv = (const float*)d_in[10];
  const float* Wo = (const float*)d_in[11];

  float* out    = (float*)d_out;
  float* kc_out = out + (size_t)L_SEQ * HID;
  float* vc_out = kc_out + (size_t)MAXP * NKV * HD;

  // Workspace map (peak 92 MiB):
  //  [0,16M):   h_bf, later attn_bf (h dead after QKV GEMM)
  //  [16M,64M): Wqkv_bf (48 MB); after QKV GEMM: Wo_bf [16M,48M)
  //  [64M,88M): qkv_bf (L x 6144 bf16, 24 MB) -- live QKV GEMM .. attn
  //  [88M,92M): vT_bf (NKV,HD,L bf16, 4 MB)   -- live postproc .. attn
  char* ws = (char*)d_ws;
  bf16_t* h_bf    = (bf16_t*)(ws + 0);
  bf16_t* attn_bf = (bf16_t*)(ws + 0);
  bf16_t* Wqkv_bf = (bf16_t*)(ws + 16777216);
  bf16_t* Wo_bf   = (bf16_t*)(ws + 16777216);
  bf16_t* qkv_bf  = (bf16_t*)(ws + 67108864);
  bf16_t* vT_bf   = (bf16_t*)(ws + 92274688);

  rmsnorm_kernel<<<L_SEQ, 256, 0, stream>>>(x, ln_w, h_bf);
  // fused Wq|Wk|Wv convert: one launch
  cvtqkv_kernel<<<(QKVD * HID) / (8 * 256), 256, 0, stream>>>(
      Wq, Wk, Wv, Wqkv_bf);

  // Fused QKV = h @ Wqkv^T -> qkv_bf (L, 6144); 24x8 = 192 blocks, 1/CU
  gemm256_kernel<0><<<dim3(QKVD / 256, L_SEQ / 256), 512, 0, stream>>>(
      h_bf, Wqkv_bf, qkv_bf, nullptr, nullptr, QKVD, HID);

  // fused rope | vtrans | cache_tail: one launch, 23040 blocks
  postproc_kernel<<<ROPE_NBLK + VT_NBLK + TAIL_NBLK, 256, 0, stream>>>(
      qkv_bf, cosT, sinT, kc_out, vc_out, vT_bf, kc_in, vc_in);

  // Wo convert (must follow QKV GEMM: Wo_bf aliases Wqkv region)
  cvt_bf16_kernel<<<(HID * HID) / (8 * 256), 256, 0, stream>>>(Wo, Wo_bf);

  // balanced 64-row-pair attention: 32 heads x 16 = 512 blocks, 2/CU
  attn_kernel<<<dim3(NH, 16), 256, 0, stream>>>(qkv_bf, vT_bf, attn_bf);

  // out = attn @ Wo^T + x ; 16x8 = 128 blocks (un-split K, round-4 form)
  gemm256_kernel<1><<<dim3(HID / 256, L_SEQ / 256), 512, 0, stream>>>(
      attn_bf, Wo_bf, nullptr, out, x, HID, HID);
}